// Round 6
// baseline (351.337 us; speedup 1.0000x reference)
//
#include <hip/hip_runtime.h>
#include <math.h>

#define BB 8
#define NCLS 16
#define NPIX 16384
#define CHN 256
#define MAXV 200
#define SORTN 2048
#define NC 8

typedef unsigned long long ull;

// ---------------- ws layout (bytes) ----------------
// 0       : double acc                (zeroed by k_plan)
// 8       : int ticket                (zeroed by k_plan)
// 64      : int plan[536]: [0]=n_view [1]=k [2]=P [3]=D,
//           chan[16]@+4, pimg[128]@+20, pcls[128]@+148, pmap[128]@+276, Lp[128]@+404
// 4096    : ull thrKey[128]
// 5120    : int gcnt[128]             (zeroed by k_plan)
// 8192    : float pos_sum[2048]       (zeroed by k_plan)
// 16384   : int counts_part[2048]     (written fully by k_cert1)
// 32768   : float cert[131072]        (512 KB)
// 1048576 : ull keybuf[128*2048]      (2 MB)
// 3145728 : float2 part[NC*8*16384]   (8 MB)

// phase 1: 8-deep batched partial top-2; chunk-0 blocks also histogram their tile
__global__ __launch_bounds__(256) void k_cert1(const float* __restrict__ feats,
                                               const int* __restrict__ predict,
                                               float2* __restrict__ part,
                                               int* __restrict__ counts_part) {
    __shared__ int h[NCLS];
    int bid = blockIdx.x;                  // BB * 16 * NC = 1024 blocks
    int chunk = bid % NC;
    int tile  = (bid / NC) % 16;
    int b     = bid / (NC * 16);
    int tid = threadIdx.x;
    int n4 = tile * 1024 + tid * 4;
    bool do_hist = (chunk == 0);
    if (do_hist) {
        if (tid < NCLS) h[tid] = 0;
        __syncthreads();
        int4 pv = *(const int4*)(predict + b * NPIX + n4);
        int pvv[4] = {pv.x, pv.y, pv.z, pv.w};
#pragma unroll
        for (int q = 0; q < 4; ++q)
            if (pvv[q] >= 0 && pvv[q] < NCLS) atomicAdd(&h[pvv[q]], 1);
    }
    const float* fb = feats + (size_t)b * CHN * NPIX + n4;
    int c0 = chunk * (CHN / NC);
    float m1[4] = {-INFINITY, -INFINITY, -INFINITY, -INFINITY};
    float m2[4] = {-INFINITY, -INFINITY, -INFINITY, -INFINITY};
    for (int cb = c0; cb < c0 + CHN / NC; cb += 8) {
        float4 xs[8];
#pragma unroll
        for (int u = 0; u < 8; ++u)
            xs[u] = *(const float4*)(fb + (size_t)(cb + u) * NPIX);
#pragma unroll
        for (int u = 0; u < 8; ++u) {
            float xv[4] = {xs[u].x, xs[u].y, xs[u].z, xs[u].w};
#pragma unroll
            for (int q = 0; q < 4; ++q) {
                float val = xv[q];
                if (val > m1[q]) { m2[q] = m1[q]; m1[q] = val; }
                else if (val > m2[q]) m2[q] = val;
            }
        }
    }
    float2* po = part + (((size_t)(b * NC + chunk)) << 14) + n4;
#pragma unroll
    for (int q = 0; q < 4; ++q) po[q] = make_float2(m1[q], m2[q]);
    if (do_hist) {
        __syncthreads();
        if (tid < NCLS) counts_part[(b * 16 + tile) * NCLS + tid] = h[tid];
    }
}

// plan + zero the small accumulators (no separate memset dispatch)
__global__ __launch_bounds__(256) void k_plan(const int* __restrict__ counts_part,
                                              int* __restrict__ plan,
                                              double* __restrict__ acc,
                                              int* __restrict__ ticket,
                                              int* __restrict__ gcnt,
                                              float* __restrict__ pos_sum) {
    __shared__ int c[128];
    __shared__ int sc[128];
    __shared__ int mn[128];
    __shared__ int present[NCLS];
    int tid = threadIdx.x;
    int* chan = plan + 4;
    int* pimg = plan + 20;
    int* pcls = plan + 148;
    int* pmap = plan + 276;
    int* Lp   = plan + 404;
    for (int i = tid; i < 2048; i += 256) pos_sum[i] = 0.f;
    if (tid < 128) gcnt[tid] = 0;
    if (tid == 0) { *acc = 0.0; *ticket = 0; }
    if (tid < NCLS) present[tid] = 0;
    if (tid < 128) {
        int b = tid >> 4, v = tid & 15, s = 0;
        for (int t2 = 0; t2 < 16; ++t2) s += counts_part[(b * 16 + t2) * NCLS + v];
        c[tid] = s;
    }
    __syncthreads();
    int e = 0;
    if (tid < 128) {
        if (c[tid] > 0) atomicOr(&present[tid & 15], 1);
        e = (c[tid] >= MAXV) ? 1 : 0;
        sc[tid] = e;
        mn[tid] = e ? c[tid] : 0x7fffffff;
    }
    __syncthreads();
    for (int off = 1; off < 128; off <<= 1) {
        int add = 0;
        if (tid < 128 && tid >= off) add = sc[tid - off];
        __syncthreads();
        if (tid < 128) sc[tid] += add;
        __syncthreads();
    }
    for (int s = 64; s > 0; s >>= 1) {
        if (tid < s) mn[tid] = min(mn[tid], mn[tid + s]);
        __syncthreads();
    }
    if (tid < 128) {
        pmap[tid] = e ? (sc[tid] - 1) : -1;
        if (e) {
            int p = sc[tid] - 1;
            pimg[p] = tid >> 4; pcls[p] = tid & 15; Lp[p] = c[tid];
        }
    }
    if (tid == 0) {
        int D = 0;
        for (int v = 0; v < NCLS; ++v) if (present[v]) chan[D++] = v;
        int nview = mn[0];
        plan[0] = nview; plan[1] = nview / 2; plan[2] = sc[127]; plan[3] = D;
    }
}

// phase 2: merge partials -> cert, AND scatter keys into per-group keybuf
__global__ __launch_bounds__(256) void k_cert2(const float2* __restrict__ part,
                                               const int* __restrict__ predict,
                                               const int* __restrict__ plan,
                                               float* __restrict__ cert,
                                               int* __restrict__ gcnt,
                                               ull* __restrict__ keybuf) {
    int tid = threadIdx.x;
    int lane = tid & 63;
    int t = blockIdx.x * 256 + tid;   // 512 blocks
    int b = t >> 14, pix = t & (NPIX - 1);
    const int* pmap = plan + 276;
    float2 pm[NC];
#pragma unroll
    for (int j = 0; j < NC; ++j)
        pm[j] = part[(((size_t)(b * NC + j)) << 14) + pix];
    float m1 = -INFINITY, m2 = -INFINITY;
#pragma unroll
    for (int j = 0; j < NC; ++j) {
        if (pm[j].x > m1) { m2 = fmaxf(m1, pm[j].y); m1 = pm[j].x; }
        else              { m2 = fmaxf(m2, pm[j].x); }
    }
    float ct = m1 - m2;
    cert[t] = ct;
    int v = predict[t];
    int p = (v >= 0 && v < NCLS) ? pmap[b * NCLS + v] : -1;
    // wave-aggregated scatter: one global atomic per (wave, class)
    for (int vv = 0; vv < NCLS; ++vv) {
        bool mine = (v == vv) && (p >= 0);
        ull mask = __ballot(mine);
        if (mask == 0) continue;
        int leader = __ffsll((long long)mask) - 1;
        if (mine) {
            int base = 0;
            if (lane == leader) base = atomicAdd(&gcnt[p], (int)__popcll(mask));
            base = __shfl(base, leader, 64);
            int pos = base + (int)__popcll(mask & ((1ull << lane) - 1));
            if (pos < SORTN) {
                unsigned int m = __float_as_uint(ct) | 0x80000000u;
                keybuf[(size_t)p * SORTN + pos] =
                    ((ull)m << 32) | (ull)(0xFFFFFFFFu - (unsigned)pix);
            }
        }
    }
}

// per-group radix-select of the kv-th largest key -> threshold
__global__ __launch_bounds__(512) void k_sel(const ull* __restrict__ keybuf,
                                             const int* __restrict__ gcnt,
                                             const int* __restrict__ plan,
                                             ull* __restrict__ thrKey) {
    __shared__ ull keys[SORTN];
    __shared__ int whist[8][256];
    __shared__ int scan[257];
    __shared__ int wtot[4];
    __shared__ ull sprefix;
    __shared__ int sremain;
    __shared__ int sdone;
    int tid = threadIdx.x;
    int lane = tid & 63, wv = tid >> 6;
    int p = blockIdx.x;
    if (p >= plan[2]) return;
    int L = gcnt[p]; if (L > SORTN) L = SORTN;
    int kv = plan[1] < L ? plan[1] : L;
    if (tid == 0) { sprefix = 0; sremain = kv; sdone = 0; }
    for (int i = tid; i < L; i += 512) keys[i] = keybuf[(size_t)p * SORTN + i];
    __syncthreads();
    for (int shift = 56; shift >= 0; shift -= 8) {
        if (sdone) break;
        for (int i = tid; i < 8 * 256; i += 512) ((int*)whist)[i] = 0;
        ull pref = sprefix;
        int rem = sremain;
        __syncthreads();
        ull maskHi = (shift == 56) ? 0ULL : (~0ULL) << (shift + 8);
        for (int i = tid; i < L; i += 512) {
            ull kk = keys[i];
            if ((kk & maskHi) == pref)
                atomicAdd(&whist[wv][(int)((kk >> shift) & 255)], 1);
        }
        __syncthreads();
        int s = 0;
        if (tid < 256) {
            for (int w = 0; w < 8; ++w) s += whist[w][tid];
            for (int off = 1; off < 64; off <<= 1) {
                int o = __shfl_down(s, off, 64);
                if (lane + off < 64) s += o;
            }
            if (lane == 0) wtot[wv] = s;
        }
        __syncthreads();
        if (tid < 256) {
            int offs = 0;
            for (int w2 = wv + 1; w2 < 4; ++w2) offs += wtot[w2];
            s += offs;
            scan[tid] = s;
            if (tid == 0) scan[256] = 0;
        }
        __syncthreads();
        if (tid < 256) {
            int nxt = scan[tid + 1];
            if (s >= rem && nxt < rem) {
                sprefix = pref | ((ull)tid << shift);
                sremain = rem - nxt;
                if (s == rem) sdone = 1;
            }
        }
        __syncthreads();
    }
    if (tid == 0) thrKey[p] = sprefix;
}

// coalesced sweep accumulation into pos_sum (unnormalized; cosines scale-inv)
__global__ __launch_bounds__(512) void k_accum(const float* __restrict__ feats,
                                               const int* __restrict__ predict,
                                               const float* __restrict__ cert,
                                               const int* __restrict__ plan,
                                               const ull* __restrict__ thrKey,
                                               float* __restrict__ pos_sum) {
    __shared__ float gacc[NCLS * 16];
    int tid = threadIdx.x;
    int t = blockIdx.x * 512 + tid;
    int b = (blockIdx.x * 512) >> 14;
    int n = t & (NPIX - 1);
    const int* chan = plan + 4;
    const int* pmap = plan + 276;
    int D = plan[3];
    if (tid < NCLS * 16) gacc[tid] = 0.f;
    __syncthreads();
    int v = predict[t];
    if (v >= 0 && v < NCLS) {
        int p = pmap[b * NCLS + v];
        if (p >= 0) {
            unsigned int m = __float_as_uint(cert[t]) | 0x80000000u;
            ull key = ((ull)m << 32) | (ull)(0xFFFFFFFFu - (unsigned)n);
            if (key >= thrKey[p]) {
                const float* fb = feats + ((size_t)(b * CHN) << 14) + n;
                if (D == 16) {
                    float x[16];
#pragma unroll
                    for (int d = 0; d < 16; ++d) x[d] = fb[(size_t)chan[d] << 14];
#pragma unroll
                    for (int d = 0; d < 16; ++d) atomicAdd(&gacc[v * 16 + d], x[d]);
                } else {
                    for (int d = 0; d < D; ++d)
                        atomicAdd(&gacc[v * 16 + d], fb[(size_t)chan[d] << 14]);
                }
            }
        }
    }
    __syncthreads();
    if (tid < NCLS * 16) {
        int p = pmap[b * NCLS + (tid >> 4)];
        if (p >= 0 && gacc[tid] != 0.f) atomicAdd(&pos_sum[p * 16 + (tid & 15)], gacc[tid]);
    }
}

// inter loss sweep + (block 0) intra pair loss + last-block writes out
__global__ __launch_bounds__(256) void k_inter(const float* __restrict__ feats,
                                               const int* __restrict__ predict,
                                               const int* __restrict__ plan,
                                               const float* __restrict__ pos_sum,
                                               double* __restrict__ acc,
                                               int* __restrict__ ticket,
                                               float* __restrict__ out) {
    __shared__ float ppd[128 * 16];
    __shared__ float nr[128];
    __shared__ double red[256];
    int tid = threadIdx.x;
    int t = blockIdx.x * 256 + tid;   // 512 blocks
    int b = t >> 14, n = t & (NPIX - 1);
    int P = plan[2], D = plan[3];
    const int* chan = plan + 4;
    const int* pmap = plan + 276;
    const int* pcls = plan + 148;
    const int* Lp = plan + 404;
    for (int i = tid; i < P * 16; i += 256) ppd[i] = pos_sum[i];
    __syncthreads();
    for (int p = tid; p < P; p += 256) {
        float s = 0;
#pragma unroll
        for (int d = 0; d < 16; ++d) { float x = ppd[p * 16 + d]; s += x * x; }
        nr[p] = sqrtf(s);
    }
    __syncthreads();
    double term = 0;
    int v = predict[t];
    if (v >= 0 && v < NCLS) {
        int p = pmap[b * NCLS + v];
        if (p >= 0) {
            const float* fb = feats + ((size_t)(b * CHN) << 14) + n;
            float dot = 0, nv = 0;
            if (D == 16) {
                float x[16];
#pragma unroll
                for (int d = 0; d < 16; ++d) x[d] = fb[(size_t)chan[d] << 14];
#pragma unroll
                for (int d = 0; d < 16; ++d) {
                    float y = ppd[p * 16 + d];
                    dot += x[d] * y; nv += x[d] * x[d];
                }
            } else {
                for (int d = 0; d < D; ++d) {
                    float x = fb[(size_t)chan[d] << 14];
                    float y = ppd[p * 16 + d];
                    dot += x * y; nv += x * x;
                }
            }
            float den = fmaxf(sqrtf(nv) * nr[p], 1e-8f);
            term = (1.0 - (double)(dot / den)) / ((double)Lp[p] * (double)P);
        }
    }
    red[tid] = term; __syncthreads();
    for (int s = 128; s > 0; s >>= 1) { if (tid < s) red[tid] += red[tid + s]; __syncthreads(); }
    if (tid == 0) atomicAdd(acc, red[0]);
    if (blockIdx.x == 0) {
        // intra pair loss on this block (pos_sum complete since k_accum finished)
        __syncthreads();
        double num = 0; int cnt = 0;
        for (int idx = tid; idx < P * P; idx += 256) {
            int i = idx / P, j = idx - i * P;
            if (pcls[i] != pcls[j]) {
                float dot = 0;
#pragma unroll
                for (int d = 0; d < 16; ++d) dot += ppd[i * 16 + d] * ppd[j * 16 + d];
                num += (double)(dot / (nr[i] * nr[j])) + 1.0;
                cnt++;
            }
        }
        red[tid] = num; __syncthreads();
        for (int s = 128; s > 0; s >>= 1) { if (tid < s) red[tid] += red[tid + s]; __syncthreads(); }
        double totnum = red[0]; __syncthreads();
        red[tid] = (double)cnt; __syncthreads();
        for (int s = 128; s > 0; s >>= 1) { if (tid < s) red[tid] += red[tid + s]; __syncthreads(); }
        if (tid == 0) atomicAdd(acc, totnum / red[0]);
    }
    // last-done block publishes the result
    __syncthreads();
    __threadfence();
    if (tid == 0) {
        int done = atomicAdd(ticket, 1);
        if (done == (int)gridDim.x - 1) {
            double v2 = atomicAdd(acc, 0.0);   // coherent read of final sum
            out[0] = (float)v2;
        }
    }
}

extern "C" void kernel_launch(void* const* d_in, const int* in_sizes, int n_in,
                              void* d_out, int out_size, void* d_ws, size_t ws_size,
                              hipStream_t stream) {
    const float* feats  = (const float*)d_in[0];
    const int* predict  = (const int*)d_in[2];
    char* ws = (char*)d_ws;
    double* acc       = (double*)ws;
    int* ticket       = (int*)(ws + 8);
    int* plan         = (int*)(ws + 64);
    ull* thrKey       = (ull*)(ws + 4096);
    int* gcnt         = (int*)(ws + 5120);
    float* pos_sum    = (float*)(ws + 8192);
    int* counts_part  = (int*)(ws + 16384);
    float* cert       = (float*)(ws + 32768);
    ull* keybuf       = (ull*)(ws + 1048576);
    float2* part      = (float2*)(ws + 3145728);
    float* out        = (float*)d_out;

    k_cert1 <<<BB * 16 * NC, 256, 0, stream>>>(feats, predict, part, counts_part);
    k_plan  <<<1,   256, 0, stream>>>(counts_part, plan, acc, ticket, gcnt, pos_sum);
    k_cert2 <<<512, 256, 0, stream>>>(part, predict, plan, cert, gcnt, keybuf);
    k_sel   <<<128, 512, 0, stream>>>(keybuf, gcnt, plan, thrKey);
    k_accum <<<256, 512, 0, stream>>>(feats, predict, cert, plan, thrKey, pos_sum);
    k_inter <<<512, 256, 0, stream>>>(feats, predict, plan, pos_sum, acc, ticket, out);
}

// Round 7
// 278.647 us; speedup vs baseline: 1.2609x; 1.2609x over previous
//
#include <hip/hip_runtime.h>
#include <math.h>

#define BB 8
#define NCLS 16
#define NPIX 16384
#define CHN 256
#define MAXV 200
#define SORTN 2048
#define NC 8

typedef unsigned long long ull;

// ---------------- ws layout (bytes) ----------------
// 0       : double acc                (zeroed by k_plan)
// 8       : int ticket                (zeroed by k_plan)
// 64      : int plan[536]: [0]=n_view [1]=k [2]=P [3]=D,
//           chan[16]@+4, pimg[128]@+20, pcls[128]@+148, pmap[128]@+276, Lp[128]@+404
// 4096    : ull thrKey[128]
// 5120    : int gcnt[128]             (zeroed by k_plan)
// 8192    : float pos_sum[2048]       (zeroed by k_plan)
// 16384   : int counts_part[2048]     (written fully by k_cert1)
// 32768   : float cert[131072]        (512 KB)
// 1048576 : ull keybuf[128*2048]      (2 MB)
// 3145728 : float2 part[NC*8*16384]   (8 MB)

// phase 1: 8-deep batched partial top-2; chunk-0 blocks also histogram their tile
__global__ __launch_bounds__(256) void k_cert1(const float* __restrict__ feats,
                                               const int* __restrict__ predict,
                                               float2* __restrict__ part,
                                               int* __restrict__ counts_part) {
    __shared__ int h[NCLS];
    int bid = blockIdx.x;                  // BB * 16 * NC = 1024 blocks
    int chunk = bid % NC;
    int tile  = (bid / NC) % 16;
    int b     = bid / (NC * 16);
    int tid = threadIdx.x;
    int n4 = tile * 1024 + tid * 4;
    bool do_hist = (chunk == 0);
    if (do_hist) {
        if (tid < NCLS) h[tid] = 0;
        __syncthreads();
        int4 pv = *(const int4*)(predict + b * NPIX + n4);
        int pvv[4] = {pv.x, pv.y, pv.z, pv.w};
#pragma unroll
        for (int q = 0; q < 4; ++q)
            if (pvv[q] >= 0 && pvv[q] < NCLS) atomicAdd(&h[pvv[q]], 1);
    }
    const float* fb = feats + (size_t)b * CHN * NPIX + n4;
    int c0 = chunk * (CHN / NC);
    float m1[4] = {-INFINITY, -INFINITY, -INFINITY, -INFINITY};
    float m2[4] = {-INFINITY, -INFINITY, -INFINITY, -INFINITY};
    for (int cb = c0; cb < c0 + CHN / NC; cb += 8) {
        float4 xs[8];
#pragma unroll
        for (int u = 0; u < 8; ++u)
            xs[u] = *(const float4*)(fb + (size_t)(cb + u) * NPIX);
#pragma unroll
        for (int u = 0; u < 8; ++u) {
            float xv[4] = {xs[u].x, xs[u].y, xs[u].z, xs[u].w};
#pragma unroll
            for (int q = 0; q < 4; ++q) {
                float val = xv[q];
                if (val > m1[q]) { m2[q] = m1[q]; m1[q] = val; }
                else if (val > m2[q]) m2[q] = val;
            }
        }
    }
    float2* po = part + (((size_t)(b * NC + chunk)) << 14) + n4;
#pragma unroll
    for (int q = 0; q < 4; ++q) po[q] = make_float2(m1[q], m2[q]);
    if (do_hist) {
        __syncthreads();
        if (tid < NCLS) counts_part[(b * 16 + tile) * NCLS + tid] = h[tid];
    }
}

// plan + zero the small accumulators (no separate memset dispatch)
__global__ __launch_bounds__(256) void k_plan(const int* __restrict__ counts_part,
                                              int* __restrict__ plan,
                                              double* __restrict__ acc,
                                              int* __restrict__ ticket,
                                              int* __restrict__ gcnt,
                                              float* __restrict__ pos_sum) {
    __shared__ int c[128];
    __shared__ int sc[128];
    __shared__ int mn[128];
    __shared__ int present[NCLS];
    int tid = threadIdx.x;
    int* chan = plan + 4;
    int* pimg = plan + 20;
    int* pcls = plan + 148;
    int* pmap = plan + 276;
    int* Lp   = plan + 404;
    for (int i = tid; i < 2048; i += 256) pos_sum[i] = 0.f;
    if (tid < 128) gcnt[tid] = 0;
    if (tid == 0) { *acc = 0.0; *ticket = 0; }
    if (tid < NCLS) present[tid] = 0;
    if (tid < 128) {
        int b = tid >> 4, v = tid & 15, s = 0;
        for (int t2 = 0; t2 < 16; ++t2) s += counts_part[(b * 16 + t2) * NCLS + v];
        c[tid] = s;
    }
    __syncthreads();
    int e = 0;
    if (tid < 128) {
        if (c[tid] > 0) atomicOr(&present[tid & 15], 1);
        e = (c[tid] >= MAXV) ? 1 : 0;
        sc[tid] = e;
        mn[tid] = e ? c[tid] : 0x7fffffff;
    }
    __syncthreads();
    for (int off = 1; off < 128; off <<= 1) {
        int add = 0;
        if (tid < 128 && tid >= off) add = sc[tid - off];
        __syncthreads();
        if (tid < 128) sc[tid] += add;
        __syncthreads();
    }
    for (int s = 64; s > 0; s >>= 1) {
        if (tid < s) mn[tid] = min(mn[tid], mn[tid + s]);
        __syncthreads();
    }
    if (tid < 128) {
        pmap[tid] = e ? (sc[tid] - 1) : -1;
        if (e) {
            int p = sc[tid] - 1;
            pimg[p] = tid >> 4; pcls[p] = tid & 15; Lp[p] = c[tid];
        }
    }
    if (tid == 0) {
        int D = 0;
        for (int v = 0; v < NCLS; ++v) if (present[v]) chan[D++] = v;
        int nview = mn[0];
        plan[0] = nview; plan[1] = nview / 2; plan[2] = sc[127]; plan[3] = D;
    }
}

// phase 2: merge partials -> cert; block-aggregated two-pass key scatter
// (one LDS atomic per thread + ONE parallel global atomic per (block,class))
__global__ __launch_bounds__(256) void k_cert2(const float2* __restrict__ part,
                                               const int* __restrict__ predict,
                                               const int* __restrict__ plan,
                                               float* __restrict__ cert,
                                               int* __restrict__ gcnt,
                                               ull* __restrict__ keybuf) {
    __shared__ int lcount[NCLS];
    __shared__ int gbase[NCLS];
    int tid = threadIdx.x;
    int t = blockIdx.x * 256 + tid;   // 512 blocks
    int b = t >> 14, pix = t & (NPIX - 1);
    const int* pmap = plan + 276;
    if (tid < NCLS) lcount[tid] = 0;
    __syncthreads();
    float2 pm[NC];
#pragma unroll
    for (int j = 0; j < NC; ++j)
        pm[j] = part[(((size_t)(b * NC + j)) << 14) + pix];
    float m1 = -INFINITY, m2 = -INFINITY;
#pragma unroll
    for (int j = 0; j < NC; ++j) {
        if (pm[j].x > m1) { m2 = fmaxf(m1, pm[j].y); m1 = pm[j].x; }
        else              { m2 = fmaxf(m2, pm[j].x); }
    }
    float ct = m1 - m2;
    cert[t] = ct;
    int v = predict[t];
    int p = (v >= 0 && v < NCLS) ? pmap[b * NCLS + v] : -1;
    int lpos = -1;
    if (p >= 0) lpos = atomicAdd(&lcount[v], 1);
    __syncthreads();
    if (tid < NCLS) {
        int cc = lcount[tid];
        int pp = pmap[b * NCLS + tid];
        gbase[tid] = (pp >= 0 && cc > 0) ? atomicAdd(&gcnt[pp], cc) : 0;
    }
    __syncthreads();
    if (p >= 0) {
        int pos = gbase[v] + lpos;
        if (pos < SORTN) {
            unsigned int m = __float_as_uint(ct) | 0x80000000u;
            keybuf[(size_t)p * SORTN + pos] =
                ((ull)m << 32) | (ull)(0xFFFFFFFFu - (unsigned)pix);
        }
    }
}

// per-group radix-select of the kv-th largest key -> threshold
__global__ __launch_bounds__(512) void k_sel(const ull* __restrict__ keybuf,
                                             const int* __restrict__ gcnt,
                                             const int* __restrict__ plan,
                                             ull* __restrict__ thrKey) {
    __shared__ ull keys[SORTN];
    __shared__ int whist[8][256];
    __shared__ int scan[257];
    __shared__ int wtot[4];
    __shared__ ull sprefix;
    __shared__ int sremain;
    __shared__ int sdone;
    int tid = threadIdx.x;
    int lane = tid & 63, wv = tid >> 6;
    int p = blockIdx.x;
    if (p >= plan[2]) return;
    int L = gcnt[p]; if (L > SORTN) L = SORTN;
    int kv = plan[1] < L ? plan[1] : L;
    if (tid == 0) { sprefix = 0; sremain = kv; sdone = 0; }
    for (int i = tid; i < L; i += 512) keys[i] = keybuf[(size_t)p * SORTN + i];
    __syncthreads();
    for (int shift = 56; shift >= 0; shift -= 8) {
        if (sdone) break;
        for (int i = tid; i < 8 * 256; i += 512) ((int*)whist)[i] = 0;
        ull pref = sprefix;
        int rem = sremain;
        __syncthreads();
        ull maskHi = (shift == 56) ? 0ULL : (~0ULL) << (shift + 8);
        for (int i = tid; i < L; i += 512) {
            ull kk = keys[i];
            if ((kk & maskHi) == pref)
                atomicAdd(&whist[wv][(int)((kk >> shift) & 255)], 1);
        }
        __syncthreads();
        int s = 0;
        if (tid < 256) {
            for (int w = 0; w < 8; ++w) s += whist[w][tid];
            for (int off = 1; off < 64; off <<= 1) {
                int o = __shfl_down(s, off, 64);
                if (lane + off < 64) s += o;
            }
            if (lane == 0) wtot[wv] = s;
        }
        __syncthreads();
        if (tid < 256) {
            int offs = 0;
            for (int w2 = wv + 1; w2 < 4; ++w2) offs += wtot[w2];
            s += offs;
            scan[tid] = s;
            if (tid == 0) scan[256] = 0;
        }
        __syncthreads();
        if (tid < 256) {
            int nxt = scan[tid + 1];
            if (s >= rem && nxt < rem) {
                sprefix = pref | ((ull)tid << shift);
                sremain = rem - nxt;
                if (s == rem) sdone = 1;
            }
        }
        __syncthreads();
    }
    if (tid == 0) thrKey[p] = sprefix;
}

// coalesced sweep accumulation into pos_sum (unnormalized; cosines scale-inv)
__global__ __launch_bounds__(512) void k_accum(const float* __restrict__ feats,
                                               const int* __restrict__ predict,
                                               const float* __restrict__ cert,
                                               const int* __restrict__ plan,
                                               const ull* __restrict__ thrKey,
                                               float* __restrict__ pos_sum) {
    __shared__ float gacc[NCLS * 16];
    int tid = threadIdx.x;
    int t = blockIdx.x * 512 + tid;
    int b = (blockIdx.x * 512) >> 14;
    int n = t & (NPIX - 1);
    const int* chan = plan + 4;
    const int* pmap = plan + 276;
    int D = plan[3];
    if (tid < NCLS * 16) gacc[tid] = 0.f;
    __syncthreads();
    int v = predict[t];
    if (v >= 0 && v < NCLS) {
        int p = pmap[b * NCLS + v];
        if (p >= 0) {
            unsigned int m = __float_as_uint(cert[t]) | 0x80000000u;
            ull key = ((ull)m << 32) | (ull)(0xFFFFFFFFu - (unsigned)n);
            if (key >= thrKey[p]) {
                const float* fb = feats + ((size_t)(b * CHN) << 14) + n;
                if (D == 16) {
                    float x[16];
#pragma unroll
                    for (int d = 0; d < 16; ++d) x[d] = fb[(size_t)chan[d] << 14];
#pragma unroll
                    for (int d = 0; d < 16; ++d) atomicAdd(&gacc[v * 16 + d], x[d]);
                } else {
                    for (int d = 0; d < D; ++d)
                        atomicAdd(&gacc[v * 16 + d], fb[(size_t)chan[d] << 14]);
                }
            }
        }
    }
    __syncthreads();
    if (tid < NCLS * 16) {
        int p = pmap[b * NCLS + (tid >> 4)];
        if (p >= 0 && gacc[tid] != 0.f) atomicAdd(&pos_sum[p * 16 + (tid & 15)], gacc[tid]);
    }
}

// inter loss sweep + (block 0) intra pair loss + last-block writes out
__global__ __launch_bounds__(256) void k_inter(const float* __restrict__ feats,
                                               const int* __restrict__ predict,
                                               const int* __restrict__ plan,
                                               const float* __restrict__ pos_sum,
                                               double* __restrict__ acc,
                                               int* __restrict__ ticket,
                                               float* __restrict__ out) {
    __shared__ float ppd[128 * 16];
    __shared__ float nr[128];
    __shared__ double red[256];
    int tid = threadIdx.x;
    int t = blockIdx.x * 256 + tid;   // 512 blocks
    int b = t >> 14, n = t & (NPIX - 1);
    int P = plan[2], D = plan[3];
    const int* chan = plan + 4;
    const int* pmap = plan + 276;
    const int* pcls = plan + 148;
    const int* Lp = plan + 404;
    for (int i = tid; i < P * 16; i += 256) ppd[i] = pos_sum[i];
    __syncthreads();
    for (int p = tid; p < P; p += 256) {
        float s = 0;
#pragma unroll
        for (int d = 0; d < 16; ++d) { float x = ppd[p * 16 + d]; s += x * x; }
        nr[p] = sqrtf(s);
    }
    __syncthreads();
    double term = 0;
    int v = predict[t];
    if (v >= 0 && v < NCLS) {
        int p = pmap[b * NCLS + v];
        if (p >= 0) {
            const float* fb = feats + ((size_t)(b * CHN) << 14) + n;
            float dot = 0, nv = 0;
            if (D == 16) {
                float x[16];
#pragma unroll
                for (int d = 0; d < 16; ++d) x[d] = fb[(size_t)chan[d] << 14];
#pragma unroll
                for (int d = 0; d < 16; ++d) {
                    float y = ppd[p * 16 + d];
                    dot += x[d] * y; nv += x[d] * x[d];
                }
            } else {
                for (int d = 0; d < D; ++d) {
                    float x = fb[(size_t)chan[d] << 14];
                    float y = ppd[p * 16 + d];
                    dot += x * y; nv += x * x;
                }
            }
            float den = fmaxf(sqrtf(nv) * nr[p], 1e-8f);
            term = (1.0 - (double)(dot / den)) / ((double)Lp[p] * (double)P);
        }
    }
    red[tid] = term; __syncthreads();
    for (int s = 128; s > 0; s >>= 1) { if (tid < s) red[tid] += red[tid + s]; __syncthreads(); }
    if (tid == 0) atomicAdd(acc, red[0]);
    if (blockIdx.x == 0) {
        __syncthreads();
        double num = 0; int cnt = 0;
        for (int idx = tid; idx < P * P; idx += 256) {
            int i = idx / P, j = idx - i * P;
            if (pcls[i] != pcls[j]) {
                float dot = 0;
#pragma unroll
                for (int d = 0; d < 16; ++d) dot += ppd[i * 16 + d] * ppd[j * 16 + d];
                num += (double)(dot / (nr[i] * nr[j])) + 1.0;
                cnt++;
            }
        }
        red[tid] = num; __syncthreads();
        for (int s = 128; s > 0; s >>= 1) { if (tid < s) red[tid] += red[tid + s]; __syncthreads(); }
        double totnum = red[0]; __syncthreads();
        red[tid] = (double)cnt; __syncthreads();
        for (int s = 128; s > 0; s >>= 1) { if (tid < s) red[tid] += red[tid + s]; __syncthreads(); }
        if (tid == 0) atomicAdd(acc, totnum / red[0]);
    }
    __syncthreads();
    __threadfence();
    if (tid == 0) {
        int done = atomicAdd(ticket, 1);
        if (done == (int)gridDim.x - 1) {
            double v2 = atomicAdd(acc, 0.0);   // coherent read of final sum
            out[0] = (float)v2;
        }
    }
}

extern "C" void kernel_launch(void* const* d_in, const int* in_sizes, int n_in,
                              void* d_out, int out_size, void* d_ws, size_t ws_size,
                              hipStream_t stream) {
    const float* feats  = (const float*)d_in[0];
    const int* predict  = (const int*)d_in[2];
    char* ws = (char*)d_ws;
    double* acc       = (double*)ws;
    int* ticket       = (int*)(ws + 8);
    int* plan         = (int*)(ws + 64);
    ull* thrKey       = (ull*)(ws + 4096);
    int* gcnt         = (int*)(ws + 5120);
    float* pos_sum    = (float*)(ws + 8192);
    int* counts_part  = (int*)(ws + 16384);
    float* cert       = (float*)(ws + 32768);
    ull* keybuf       = (ull*)(ws + 1048576);
    float2* part      = (float2*)(ws + 3145728);
    float* out        = (float*)d_out;

    k_cert1 <<<BB * 16 * NC, 256, 0, stream>>>(feats, predict, part, counts_part);
    k_plan  <<<1,   256, 0, stream>>>(counts_part, plan, acc, ticket, gcnt, pos_sum);
    k_cert2 <<<512, 256, 0, stream>>>(part, predict, plan, cert, gcnt, keybuf);
    k_sel   <<<128, 512, 0, stream>>>(keybuf, gcnt, plan, thrKey);
    k_accum <<<256, 512, 0, stream>>>(feats, predict, cert, plan, thrKey, pos_sum);
    k_inter <<<512, 256, 0, stream>>>(feats, predict, plan, pos_sum, acc, ticket, out);
}